// Round 8
// baseline (215.370 us; speedup 1.0000x reference)
//
#include <hip/hip_runtime.h>

// VectorQuantizer: fp32 buffers. in [32,64,64,64] NCHW, emb [512,64], out
// fp32. Must match numpy fp32 distance argmin bit-for-bit.
// Proven numerics (R15/R16/R17, absmax 0.0 on HW x3): single-plane fp16
// filter -- codebook staged as fp16(e*2^14) (normal range; |e|<=1/512),
// x as plain fp16; acc = 2^14*dot - 2^13*b2 via MFMA acc init; index packed
// in low 9 mantissa bits; med3/max top-3 net; HMARGIN 10.0 >= 2*eps
// (eps<=~4.8 worst case). Ambiguous rows resolved by bit-exact numpy fp32
// replica (per-lane top-2 re-rank; wave-cooperative full rescan).
// R12-R17 post-mortem: all pipes <20% busy; wall ~= 8*T_block/concurrency
// (R12 2 blocks/CU=81us, R17 1.25=150us). T_block ~20us is barrier-gated
// latency: every __syncthreads makes 4 waves wait for the slowest phase,
// incl. the ~2us single-wave serial rescan (frequent at fp16 margins).
// R18: 1-WAVE BLOCKS, ZERO BARRIERS. 4096 blocks x 64 thr; each wave owns
// 32 rows x all 512 cols (per-wave loads = R12; chip-wide codebook traffic
// = half of R12, L2-resident). Wave-local everything via the R13-proven
// machinery (shuffle-transpose, ballot rescan, shfl fold). LDS 10.4KB,
// ~16-20 resident waves/CU -> latency hidden by TLP, rescans interleave.

#define NEMB 512
#define DIM 64
#define ROWS 32  // rows per (single-wave) block
#define HMARGIN 10.0f  // margin in scaled max-domain acc = 2^14*(dot - b2/2)

typedef unsigned int u32;
typedef unsigned short u16;
typedef __attribute__((ext_vector_type(8))) _Float16 f16x8;
typedef __attribute__((ext_vector_type(4))) float f32x4;

__device__ __forceinline__ u16 f2hbits(float f) {  // fp32 -> fp16 bits (RNE)
  union { _Float16 h; u16 u; } cv;
  cv.h = (_Float16)f;
  return cv.u;
}
__device__ __forceinline__ float fmed3(float a, float b, float c) {
  return __builtin_amdgcn_fmed3f(a, b, c);
}

// ---- prep: swizzled single-plane scaled-fp16 codebook + numpy-replica b2 --
// u16 layout: g*1024 + f*512 + r*32 + e ; g=row>>4, r=row&15, f=k>>5, e=k&31.
// A wave's 16-col fragment load at fixed (g,f) is 1KB contiguous (16B/lane).
// 128 blocks x 256 thr; b2 via shfl_xor tree == numpy pairwise-8 bit-exactly
// (proven R13-R17, absmax 0.0).
__global__ void vq_prep(const float* __restrict__ emb, u16* __restrict__ swz,
                        float* __restrict__ b2) {
#pragma clang fp contract(off)
  const int gtid = blockIdx.x * 256 + threadIdx.x;  // 0..32767
  {  // swz element task: e scaled by 2^14 (exact pow2), then RNE to fp16
    const int row = gtid >> 6, k = gtid & 63;
    const float ev = emb[gtid];
    swz[((row >> 4) << 10) + ((k >> 5) << 9) + ((row & 15) << 5) + (k & 31)] =
        f2hbits(ev * 16384.0f);
  }
  if (gtid < NEMB * 8) {  // b2 task: row = gtid>>3, j = gtid&7
    const int row = gtid >> 3, j = gtid & 7;
    const float* e = emb + (row << 6);
    float acc = e[j] * e[j];
#pragma unroll
    for (int i = 8; i < DIM; i += 8) acc = acc + e[i + j] * e[i + j];
    acc = acc + __shfl_xor(acc, 1);  // j=0: rr0+rr1
    acc = acc + __shfl_xor(acc, 2);  // j=0: (rr0+rr1)+(rr2+rr3)
    acc = acc + __shfl_xor(acc, 4);  // j=0: full pairwise-8 combine
    if (j == 0) b2[row] = acc;
  }
}

// ---- main kernel: ONE WAVE per block, 32 rows x 512 cols, no barriers ----
__global__ __launch_bounds__(64, 1) void vq_mfma(
    const float* __restrict__ in, const float* __restrict__ emb,
    const u16* __restrict__ swz, const float* __restrict__ b2g,
    float* __restrict__ out) {
#pragma clang fp contract(off)
  __shared__ float xs[ROWS][DIM + 1];  // stride 65: conflict-free row/col
  __shared__ float b2s[NEMB];

  const int lane = threadIdx.x;  // 64 threads == 1 wave
  const int blk = blockIdx.x;    // 4096
  const int b = blk >> 7;
  const int hw0 = (blk & 127) << 5;
  const float* xbase = in + ((size_t)b << 18) + hw0;

  // stage b2 (8 coalesced loads)
#pragma unroll
  for (int i = 0; i < 8; ++i) b2s[(i << 6) + lane] = b2g[(i << 6) + lane];

  const int r16 = lane & 15;   // hw-within-16 / col-class
  const int cg = lane >> 4;    // 0..3
  const int rowl = r16;
  const int quad = cg;

  {  // stage x tile: 32 rows x 64 ch; per instr 4 x 64B segments (coalesced)
#pragma unroll
    for (int i = 0; i < 32; ++i) {
      const int c = cg + ((i & 15) << 2);
      const int hw = r16 + ((i >> 4) << 4);
      xs[hw][c] = xbase[((size_t)c << 12) + hw];
    }
  }

  // a2 numpy pairwise-8 replica for this lane's two rows (quad-redundant)
  float a2r[2];
#pragma unroll
  for (int ta = 0; ta < 2; ++ta) {
    const float* x = xs[(ta << 4) + rowl];
    float rr[8];
#pragma unroll
    for (int j = 0; j < 8; ++j) {
      float acc = x[j] * x[j];
#pragma unroll
      for (int i = 8; i < DIM; i += 8) acc = acc + x[i + j] * x[i + j];
      rr[j] = acc;
    }
    a2r[ta] = ((rr[0] + rr[1]) + (rr[2] + rr[3])) + ((rr[4] + rr[5]) + (rr[6] + rr[7]));
  }

  // A fragments (plain fp16 of x): A[m=rowl][k=quad*8+j], 2 row-tiles
  f16x8 ah[2][2];
#pragma unroll
  for (int ta = 0; ta < 2; ++ta) {
    const float* xr = xs[(ta << 4) + rowl];
#pragma unroll
    for (int f = 0; f < 2; ++f) {
      const int k0 = (f << 5) + (quad << 3);
      f16x8 vh;
#pragma unroll
      for (int j = 0; j < 8; ++j) vh[j] = (_Float16)xr[k0 + j];
      ah[ta][f] = vh;
    }
  }

  // ---- single pass over ALL 512 cols: streaming top-3 MAXIMA of
  // acc = 2^14*dot - 2^13*b2, index packed in low 9 mantissa bits ----
  float v1[8], v2[8], v3[8];
#pragma unroll
  for (int i = 0; i < 8; ++i) { v1[i] = -3.0e38f; v2[i] = -3.0e38f; v3[i] = -3.0e38f; }

  const int off = (rowl << 5) + (quad << 3);

  // preload group 0; rolled loop (unroll 1) with 1-deep clamped prefetch
  f16x8 nh0 = *(const f16x8*)(swz + off);
  f16x8 nh1 = *(const f16x8*)(swz + 512 + off);

#pragma unroll 1
  for (int t = 0; t < 32; ++t) {
    const f16x8 bh0 = nh0, bh1 = nh1;
    {  // prefetch next group (clamped: last iter re-loads, harmless)
      const int tn = t < 31 ? t + 1 : 31;
      const u16* gb = swz + (tn << 10);
      nh0 = *(const f16x8*)(gb + off);
      nh1 = *(const f16x8*)(gb + 512 + off);
    }
    const int n = (t << 4) + rowl;
    const float nb2 = b2s[n] * -8192.0f;  // -2^13*b2 (exact pow2 scale)
    const u32 nbits = (u32)n;
#pragma unroll
    for (int ta = 0; ta < 2; ++ta) {
      f32x4 acc = {nb2, nb2, nb2, nb2};
      acc = __builtin_amdgcn_mfma_f32_16x16x32_f16(ah[ta][0], bh0, acc, 0, 0, 0);
      acc = __builtin_amdgcn_mfma_f32_16x16x32_f16(ah[ta][1], bh1, acc, 0, 0, 0);
#pragma unroll
      for (int r = 0; r < 4; ++r) {
        const int i = (ta << 2) + r;
        const float cp =
            __uint_as_float((__float_as_uint(acc[r]) & 0xFFFFFE00u) | nbits);
        v3[i] = fmed3(v2[i], cp, v3[i]);
        v2[i] = fmed3(v1[i], cp, v2[i]);
        v1[i] = fmaxf(v1[i], cp);
      }
    }
  }

  // butterfly top-3 merge across the 16 column classes (max domain)
#pragma unroll
  for (int m = 1; m < 16; m <<= 1) {
#pragma unroll
    for (int i = 0; i < 8; ++i) {
      const float o1 = __shfl_xor(v1[i], m);
      const float o2 = __shfl_xor(v2[i], m);
      const float o3 = __shfl_xor(v3[i], m);
      v3[i] = fmed3(v2[i], o1, v3[i]);
      v2[i] = fmed3(v1[i], o1, v2[i]);
      v1[i] = fmaxf(v1[i], o1);
      v3[i] = fmed3(v2[i], o2, v3[i]);
      v2[i] = fmed3(v1[i], o2, v2[i]);
      v3[i] = fmaxf(v3[i], o3);
    }
  }

  // shuffle-transpose (R13-proven): lane L receives top-3 of rows
  // ta*16 + (L&15); source lane = 16*((L&15)>>2), element = ta*4 + (L&3)
  float m1[2], m2v[2], m3[2];
  {
    const int srcl = ((lane >> 2) & 3) << 4;
    const int rm = lane & 3;
#pragma unroll
    for (int ta = 0; ta < 2; ++ta) {
      float t0 = __shfl(v1[(ta << 2) + 0], srcl), t1 = __shfl(v1[(ta << 2) + 1], srcl);
      float t2 = __shfl(v1[(ta << 2) + 2], srcl), t3 = __shfl(v1[(ta << 2) + 3], srcl);
      m1[ta] = rm == 0 ? t0 : rm == 1 ? t1 : rm == 2 ? t2 : t3;
      t0 = __shfl(v2[(ta << 2) + 0], srcl); t1 = __shfl(v2[(ta << 2) + 1], srcl);
      t2 = __shfl(v2[(ta << 2) + 2], srcl); t3 = __shfl(v2[(ta << 2) + 3], srcl);
      m2v[ta] = rm == 0 ? t0 : rm == 1 ? t1 : rm == 2 ? t2 : t3;
      t0 = __shfl(v3[(ta << 2) + 0], srcl); t1 = __shfl(v3[(ta << 2) + 1], srcl);
      t2 = __shfl(v3[(ta << 2) + 2], srcl); t3 = __shfl(v3[(ta << 2) + 3], srcl);
      m3[ta] = rm == 0 ? t0 : rm == 1 ? t1 : rm == 2 ? t2 : t3;
    }
  }

  // ---- per-lane decision (scaled max domain), wave-local ----
  int jw[2];
  bool nf[2];
#pragma unroll
  for (int ta = 0; ta < 2; ++ta) {
    const int j1 = (int)(__float_as_uint(m1[ta]) & 0x1FFu);
    const int j2 = (int)(__float_as_uint(m2v[ta]) & 0x1FFu);
    jw[ta] = j1;
    nf[ta] = false;
    if (m2v[ta] < m1[ta] - HMARGIN) {
      // unambiguous
    } else if (m3[ta] < m1[ta] - HMARGIN) {
      // true argmin in {j1,j2}: exact numpy fp32 re-rank, first-min tie rule
      const float* x = xs[(ta << 4) + rowl];
      const float* e1p = emb + (j1 << 6);
      const float* e2p = emb + (j2 << 6);
      float acc1 = 0.f, acc2 = 0.f;
#pragma unroll
      for (int j = 0; j < DIM; ++j) {
        acc1 = fmaf(x[j], e1p[j], acc1);
        acc2 = fmaf(x[j], e2p[j], acc2);
      }
      const float t1 = a2r[ta] + b2s[j1];
      const float t2 = a2r[ta] + b2s[j2];
      const float d1 = t1 - 2.0f * acc1;
      const float d2 = t2 - 2.0f * acc2;
      jw[ta] = (d2 < d1 || (d2 == d1 && j2 < j1)) ? j2 : j1;
    } else {
      nf[ta] = true;  // >=3 within margin: full exact rescan
    }
  }

  // ---- fallback: wave-cooperative bit-exact numpy fp32 rescan ----
#pragma unroll
  for (int ta = 0; ta < 2; ++ta) {
    unsigned long long fmask = __ballot(nf[ta] && lane < 16);
    while (fmask) {
      const int r = (int)__builtin_ctzll(fmask);
      fmask &= fmask - 1;
      const float a2v = __shfl(a2r[ta], r);
      const float* x = xs[(ta << 4) + r];  // broadcast LDS reads
      float bd = 3.0e38f;
      int bi = 1 << 30;
#pragma unroll 1
      for (int c = 0; c < 8; ++c) {
        const int k = (c << 6) + lane;
        const float* e = emb + (k << 6);
        float acc = 0.f;
#pragma unroll
        for (int j = 0; j < DIM; ++j) acc = fmaf(x[j], e[j], acc);
        const float tt = a2v + b2s[k];  // fl(a2+b2)
        const float u = 2.0f * acc;     // fl(2ab)
        const float d = tt - u;         // fl(t-u)
        if (d < bd || (d == bd && k < bi)) { bd = d; bi = k; }
      }
#pragma unroll
      for (int m = 1; m < 64; m <<= 1) {  // numpy first-min tie rule
        const float od = __shfl_xor(bd, m);
        const int oi = __shfl_xor(bi, m);
        if (od < bd || (od == bd && oi < bi)) { bd = od; bi = oi; }
      }
      if (lane == r) jw[ta] = bi;
    }
  }

  {  // fold q into xs in place: batched 8-row groups, fl(x + fl(q-x))
#pragma unroll
    for (int ta = 0; ta < 2; ++ta)
#pragma unroll
      for (int hb = 0; hb < 2; ++hb) {
        int wn[8];
#pragma unroll
        for (int r = 0; r < 8; ++r) wn[r] = __shfl(jw[ta], (hb << 3) + r);
        float qv[8];
#pragma unroll
        for (int r = 0; r < 8; ++r) qv[r] = emb[(wn[r] << 6) + lane];
#pragma unroll
        for (int r = 0; r < 8; ++r) {
          const int row = (ta << 4) + (hb << 3) + r;
          const float xv = xs[row][lane];
          xs[row][lane] = xv + (qv[r] - xv);
        }
      }
  }

  {  // store: same 4x64B-segment mapping as the load (coalesced)
    float* obase = out + ((size_t)b << 18) + hw0;
#pragma unroll
    for (int i = 0; i < 32; ++i) {
      const int c = cg + ((i & 15) << 2);
      const int hw = r16 + ((i >> 4) << 4);
      obase[((size_t)c << 12) + hw] = xs[hw][c];
    }
  }
}

// ---- fallback (R3, passed absmax 0.0): used only if ws too small ----
__global__ __launch_bounds__(256, 2) void vq_exact(
    const float* __restrict__ in, const float* __restrict__ emb,
    float* __restrict__ out, int nvec) {
#pragma clang fp contract(off)
  __shared__ float b2s[NEMB];
  for (int r = threadIdx.x; r < NEMB; r += 256) {
    const float* e = emb + r * DIM;
    float rr[8];
#pragma unroll
    for (int j = 0; j < 8; ++j) {
      float acc = e[j] * e[j];
#pragma unroll
      for (int i = 8; i < DIM; i += 8) acc = acc + e[i + j] * e[i + j];
      rr[j] = acc;
    }
    b2s[r] = ((rr[0] + rr[1]) + (rr[2] + rr[3])) + ((rr[4] + rr[5]) + (rr[6] + rr[7]));
  }
  __syncthreads();
  const int vec = blockIdx.x * 256 + threadIdx.x;
  if (vec >= nvec) return;
  const int b = vec >> 12, hw = vec & 4095;
  const float* xp = in + ((size_t)b << 18) + hw;
  float x[DIM];
#pragma unroll
  for (int j = 0; j < DIM; ++j) x[j] = xp[(size_t)j << 12];
  float a2;
  {
    float rr[8];
#pragma unroll
    for (int j = 0; j < 8; ++j) {
      float acc = x[j] * x[j];
#pragma unroll
      for (int i = 8; i < DIM; i += 8) acc = acc + x[i + j] * x[i + j];
      rr[j] = acc;
    }
    a2 = ((rr[0] + rr[1]) + (rr[2] + rr[3])) + ((rr[4] + rr[5]) + (rr[6] + rr[7]));
  }
  float best = 3.0e38f;
  int bi = 0;
  for (int k0 = 0; k0 < NEMB; k0 += 4) {
    const float *e0 = emb + ((k0 + 0) << 6), *e1 = emb + ((k0 + 1) << 6);
    const float *e2 = emb + ((k0 + 2) << 6), *e3 = emb + ((k0 + 3) << 6);
    float c0 = 0.f, c1 = 0.f, c2 = 0.f, c3 = 0.f;
#pragma unroll
    for (int j = 0; j < DIM; ++j) {
      const float xj = x[j];
      c0 = fmaf(xj, e0[j], c0); c1 = fmaf(xj, e1[j], c1);
      c2 = fmaf(xj, e2[j], c2); c3 = fmaf(xj, e3[j], c3);
    }
    float cc[4] = {c0, c1, c2, c3};
#pragma unroll
    for (int q = 0; q < 4; ++q) {
      const float t = a2 + b2s[k0 + q];
      const float u = 2.0f * cc[q];
      const float d = t - u;
      if (d < best) { best = d; bi = k0 + q; }
    }
  }
  const float* ew = emb + (bi << 6);
  float* op = out + ((size_t)b << 18) + hw;
#pragma unroll
  for (int c = 0; c < DIM; ++c) {
    const float xv = x[c];
    op[(size_t)c << 12] = xv + (ew[c] - xv);
  }
}

extern "C" void kernel_launch(void* const* d_in, const int* in_sizes, int n_in,
                              void* d_out, int out_size, void* d_ws, size_t ws_size,
                              hipStream_t stream) {
  const float* in;
  const float* emb;
  int in_elems;
  if (n_in >= 2 && in_sizes[0] == NEMB * DIM && in_sizes[1] != NEMB * DIM) {
    emb = (const float*)d_in[0]; in = (const float*)d_in[1]; in_elems = in_sizes[1];
  } else {
    in = (const float*)d_in[0]; emb = (const float*)d_in[1]; in_elems = in_sizes[0];
  }
  float* out = (float*)d_out;
  const int nvec = in_elems / DIM;
  const size_t swzB = (size_t)NEMB * DIM * sizeof(u16);  // single fp16 plane
  const size_t need = swzB + NEMB * sizeof(float);

  if (ws_size >= need && d_ws != nullptr && (nvec % ROWS) == 0 &&
      (in_elems % (DIM * 4096)) == 0) {
    u16* swz = (u16*)d_ws;
    float* b2 = (float*)((char*)d_ws + swzB);
    vq_prep<<<dim3(NEMB * DIM / 256), dim3(256), 0, stream>>>(emb, swz, b2);
    vq_mfma<<<dim3(nvec / ROWS), dim3(64), 0, stream>>>(in, emb, swz, b2, out);
  } else {
    vq_exact<<<dim3((nvec + 255) / 256), dim3(256), 0, stream>>>(in, emb, out, nvec);
  }
}

// Round 9
// 160.161 us; speedup vs baseline: 1.3447x; 1.3447x over previous
//
#include <hip/hip_runtime.h>

// VectorQuantizer: fp32 buffers. in [32,64,64,64] NCHW, emb [512,64], out
// fp32. Must match numpy fp32 distance argmin bit-for-bit.
// Proven numerics (R11/R12, absmax 0.0, 80.7us best): bf16 hi/lo split
// (exact products), max-domain filter acc' = dot - b2/2 via MFMA acc init,
// index packed in low 9 mantissa bits, med3/max top-3 net, HMARGIN 1.45e-4;
// ambiguous rows -> bit-exact numpy fp32 replica (per-thread top-2 re-rank
// ~5% of rows, wave-cooperative full rescan ~0.1%).
// R15-R18 post-mortem: fp16 single-plane halved pipe work but margin/gap
// ratio exploded fallback rates (every wave paid divergent re-rank+rescan)
// -> 150-157us. Zero-barrier R18 disproved the barrier theory. Filter
// precision is not a free knob. Reverting to bf16 hi/lo.
// R19: R12 verbatim numerics, HALF-SIZE BLOCKS: 32 rows/block, 4096 blocks
// (16/CU vs R12's 4/CU). Wave = 1 row-tile x 1 col-half (1 ta). Per-block
// latency ~halves (half MFMA/select/staging, same barriers), LDS 11.7KB ->
// more concurrent blocks/CU -> latency actually overlapped.

#define NEMB 512
#define DIM 64
#define ROWS 32
#define HMARGIN 1.45e-4f  // margin in acc' = -c2/2 (max) domain

typedef unsigned int u32;
typedef unsigned short u16;
typedef __attribute__((ext_vector_type(8))) short bf16x8;
typedef __attribute__((ext_vector_type(4))) float f32x4;

__device__ __forceinline__ u32 f2bfbits(float f) {  // fp32 -> bf16 bits (RNE)
  u32 u = __float_as_uint(f);
  return (u + 0x7FFFu + ((u >> 16) & 1u)) >> 16;
}
__device__ __forceinline__ float bfbits2f(u32 b) {
  return __uint_as_float(b << 16);
}
__device__ __forceinline__ float fmed3(float a, float b, float c) {
  return __builtin_amdgcn_fmed3f(a, b, c);
}

// ---- prep: swizzled hi/lo bf16 codebook + exact numpy-replica b2 ----
// off(g,p,f,r,e) = g*2048 + p*1024 + f*512 + r*32 + e   (u16 units)
//   g=row>>4, r=row&15, p=plane(0 hi,1 lo), f=k>>5, e=k&31.
// 128 blocks x 256 thr (R13-proven parallel form, absmax 0.0); b2 via
// shfl_xor tree == numpy pairwise-8 bit-exactly.
__global__ void vq_prep(const float* __restrict__ emb, u16* __restrict__ swz,
                        float* __restrict__ b2) {
#pragma clang fp contract(off)
  const int gtid = blockIdx.x * 256 + threadIdx.x;  // 0..32767
  {  // swz element task
    const int row = gtid >> 6, k = gtid & 63;
    const float ev = emb[gtid];
    const u32 h = f2bfbits(ev);
    const float res = ev - bfbits2f(h);  // exact (Sterbenz)
    u16* gb = swz + ((row >> 4) << 11) + ((row & 15) << 5);
    const int off2 = ((k >> 5) << 9) + (k & 31);
    gb[off2] = (u16)h;                     // hi plane
    gb[1024 + off2] = (u16)f2bfbits(res);  // lo plane
  }
  if (gtid < NEMB * 8) {  // b2 task: row = gtid>>3, j = gtid&7
    const int row = gtid >> 3, j = gtid & 7;
    const float* e = emb + (row << 6);
    float acc = e[j] * e[j];
#pragma unroll
    for (int i = 8; i < DIM; i += 8) acc = acc + e[i + j] * e[i + j];
    acc = acc + __shfl_xor(acc, 1);  // j=0: rr0+rr1
    acc = acc + __shfl_xor(acc, 2);  // j=0: (rr0+rr1)+(rr2+rr3)
    acc = acc + __shfl_xor(acc, 4);  // j=0: full pairwise-8 combine
    if (j == 0) b2[row] = acc;
  }
}

// ---- main kernel: 32 rows/block, 4 waves.
// wave wv: row-tile rh=wv&1 (16 rows), col-half ch=wv>>1 (256 cols).
__global__ __launch_bounds__(256, 1) void vq_mfma(
    const float* __restrict__ in, const float* __restrict__ emb,
    const u16* __restrict__ swz, const float* __restrict__ b2g,
    float* __restrict__ out) {
#pragma clang fp contract(off)
  __shared__ float xs[ROWS][DIM + 2];
  __shared__ float a2s[ROWS];
  __shared__ float b2s[NEMB];
  __shared__ float wsv1[ROWS][2], wsv2[ROWS][2], wsv3[ROWS][2];
  __shared__ int win[ROWS];
  __shared__ int queue[ROWS];
  __shared__ int qcnt;

  const int tid = threadIdx.x;
  const int blk = blockIdx.x;
  const int b = blk >> 7;                 // 128 blocks per image
  const int hw0 = (blk & 127) << 5;       // 32 hw rows per block
  const float* xbase = in + ((size_t)b << 18) + hw0;

  for (int i = tid; i < NEMB; i += 256) b2s[i] = b2g[i];
  if (tid == 0) qcnt = 0;

  {  // stage x tile: 32 rows x 64 ch; 256 thr x 8 elems, coalesced segments
    const int h = tid & 31, cg = tid >> 5;
#pragma unroll
    for (int i = 0; i < 8; ++i) {
      const int c = cg + (i << 3);
      xs[h][c] = xbase[((size_t)c << 12) + h];
    }
  }
  __syncthreads();

  if (tid < ROWS) {  // a2 numpy pairwise-8 replica (re-rank input)
    const float* x = xs[tid];
    float rr[8];
#pragma unroll
    for (int j = 0; j < 8; ++j) {
      float acc = x[j] * x[j];
#pragma unroll
      for (int i = 8; i < DIM; i += 8) acc = acc + x[i + j] * x[i + j];
      rr[j] = acc;
    }
    a2s[tid] = ((rr[0] + rr[1]) + (rr[2] + rr[3])) + ((rr[4] + rr[5]) + (rr[6] + rr[7]));
  }

  const int lane = tid & 63;
  const int wv = tid >> 6;
  const int rh = wv & 1;   // row-tile
  const int ch = wv >> 1;  // col-half
  const int rowl = lane & 15;
  const int quad = lane >> 4;

  // A fragments for this wave's single row-tile: A[m=lane&15][k=quad*8+j]
  bf16x8 ah[2], al[2];
#pragma unroll
  for (int f = 0; f < 2; ++f) {
    const float* xr = xs[(rh << 4) + rowl];
    const int k0 = (f << 5) + (quad << 3);
    bf16x8 vh, vl;
#pragma unroll
    for (int j = 0; j < 8; ++j) {
      const float xv = xr[k0 + j];
      const u32 h = f2bfbits(xv);
      const float res = xv - bfbits2f(h);  // exact
      vh[j] = (short)h;
      vl[j] = (short)f2bfbits(res);
    }
    ah[f] = vh;
    al[f] = vl;
  }

  // ---- single pass over 256 cols: streaming top-3 MAXIMA of
  // acc' = dot - b2/2, index packed in low 9 mantissa bits ----
  float v1[4], v2[4], v3[4];
#pragma unroll
  for (int i = 0; i < 4; ++i) { v1[i] = -3.0e38f; v2[i] = -3.0e38f; v3[i] = -3.0e38f; }

  const u16* cbase = swz + ((size_t)(ch << 4) << 11);
  const int off = (rowl << 5) + (quad << 3);

  // 2-deep prefetch: two register sets, manual 2-phase rolled loop (R12)
  bf16x8 Ah0 = *(const bf16x8*)(cbase + off);
  bf16x8 Ah1 = *(const bf16x8*)(cbase + 512 + off);
  bf16x8 Al0 = *(const bf16x8*)(cbase + 1024 + off);
  bf16x8 Al1 = *(const bf16x8*)(cbase + 1536 + off);
  bf16x8 Bh0 = *(const bf16x8*)(cbase + 2048 + off);
  bf16x8 Bh1 = *(const bf16x8*)(cbase + 2048 + 512 + off);
  bf16x8 Bl0 = *(const bf16x8*)(cbase + 2048 + 1024 + off);
  bf16x8 Bl1 = *(const bf16x8*)(cbase + 2048 + 1536 + off);

#define VQ_PHASE(TT, PH0, PH1, PL0, PL1)                                      \
  {                                                                           \
    const bf16x8 bh0 = PH0, bh1 = PH1, bl0 = PL0, bl1 = PL1;                  \
    const int tn = (TT) + 2 < 16 ? (TT) + 2 : (TT); /* clamped reload */      \
    const u16* gb = cbase + (tn << 11);                                       \
    PH0 = *(const bf16x8*)(gb + off);                                         \
    PH1 = *(const bf16x8*)(gb + 512 + off);                                   \
    PL0 = *(const bf16x8*)(gb + 1024 + off);                                  \
    PL1 = *(const bf16x8*)(gb + 1536 + off);                                  \
    const int n = (ch << 8) + ((TT) << 4) + rowl;                             \
    const float nb2 = b2s[n] * -0.5f;                                         \
    const u32 nbits = (u32)n;                                                 \
    f32x4 acc = {nb2, nb2, nb2, nb2};                                         \
    acc = __builtin_amdgcn_mfma_f32_16x16x32_bf16(ah[0], bh0, acc, 0, 0, 0);  \
    acc = __builtin_amdgcn_mfma_f32_16x16x32_bf16(ah[1], bh1, acc, 0, 0, 0);  \
    acc = __builtin_amdgcn_mfma_f32_16x16x32_bf16(ah[0], bl0, acc, 0, 0, 0);  \
    acc = __builtin_amdgcn_mfma_f32_16x16x32_bf16(ah[1], bl1, acc, 0, 0, 0);  \
    acc = __builtin_amdgcn_mfma_f32_16x16x32_bf16(al[0], bh0, acc, 0, 0, 0);  \
    acc = __builtin_amdgcn_mfma_f32_16x16x32_bf16(al[1], bh1, acc, 0, 0, 0);  \
    _Pragma("unroll") for (int r = 0; r < 4; ++r) {                           \
      const float cp =                                                        \
          __uint_as_float((__float_as_uint(acc[r]) & 0xFFFFFE00u) | nbits);   \
      v3[r] = fmed3(v2[r], cp, v3[r]);                                        \
      v2[r] = fmed3(v1[r], cp, v2[r]);                                        \
      v1[r] = fmaxf(v1[r], cp);                                               \
    }                                                                         \
  }

#pragma unroll 1
  for (int t = 0; t < 16; t += 2) {
    VQ_PHASE(t, Ah0, Ah1, Al0, Al1);
    VQ_PHASE(t + 1, Bh0, Bh1, Bl0, Bl1);
  }
#undef VQ_PHASE

  // butterfly top-3 merge across the 16 column lanes (max domain); packed
  // values carry their indices, so the merge is pure med3/max
#pragma unroll
  for (int m = 1; m < 16; m <<= 1) {
#pragma unroll
    for (int i = 0; i < 4; ++i) {
      const float o1 = __shfl_xor(v1[i], m);
      const float o2 = __shfl_xor(v2[i], m);
      const float o3 = __shfl_xor(v3[i], m);
      v3[i] = fmed3(v2[i], o1, v3[i]);
      v2[i] = fmed3(v1[i], o1, v2[i]);
      v1[i] = fmaxf(v1[i], o1);
      v3[i] = fmed3(v2[i], o2, v3[i]);
      v2[i] = fmed3(v1[i], o2, v2[i]);
      v3[i] = fmaxf(v3[i], o3);
    }
  }
  if (rowl == 0) {  // publish per col-half slot
#pragma unroll
    for (int r = 0; r < 4; ++r) {
      const int row = (rh << 4) + (quad << 2) + r;
      wsv1[row][ch] = v1[r]; wsv2[row][ch] = v2[r]; wsv3[row][ch] = v3[r];
    }
  }
  __syncthreads();

  // ---- cross-half merge + decision (max domain) ----
  if (tid < ROWS) {
    float m1 = wsv1[tid][0], m2v = wsv2[tid][0], m3 = wsv3[tid][0];
    const float u1 = wsv1[tid][1], u2 = wsv2[tid][1], u3 = wsv3[tid][1];
    m3 = fmed3(m2v, u1, m3);
    m2v = fmed3(m1, u1, m2v);
    m1 = fmaxf(m1, u1);
    m3 = fmed3(m2v, u2, m3);
    m2v = fmed3(m1, u2, m2v);
    m3 = fmaxf(m3, u3);
    const int j1 = (int)(__float_as_uint(m1) & 0x1FFu);
    const int j2 = (int)(__float_as_uint(m2v) & 0x1FFu);

    if (m2v < m1 - HMARGIN) {
      win[tid] = j1;  // unambiguous
    } else if (m3 < m1 - HMARGIN) {
      // true argmin in {j1,j2}: exact numpy fp32 re-rank, first-min tie rule
      const float a2 = a2s[tid];
      const float* x = xs[tid];
      const float* e1p = emb + (j1 << 6);
      const float* e2p = emb + (j2 << 6);
      float acc1 = 0.f, acc2 = 0.f;
#pragma unroll
      for (int j = 0; j < DIM; ++j) {
        acc1 = fmaf(x[j], e1p[j], acc1);
        acc2 = fmaf(x[j], e2p[j], acc2);
      }
      const float t1 = a2 + b2s[j1];
      const float t2 = a2 + b2s[j2];
      const float d1 = t1 - 2.0f * acc1;
      const float d2 = t2 - 2.0f * acc2;
      win[tid] = (d2 < d1 || (d2 == d1 && j2 < j1)) ? j2 : j1;
    } else {  // >=3 within margin: full exact rescan (rare)
      const int p = atomicAdd(&qcnt, 1);
      queue[p] = tid;
    }
  }
  __syncthreads();

  // ---- rare fallback: wave-cooperative bit-exact numpy fp32 rescan ----
  const int nq = qcnt;
  for (int qi = wv; qi < nq; qi += 4) {
    const int row = queue[qi];
    const float a2 = a2s[row];
    const float* x = xs[row];  // broadcast LDS reads
    float bd = 3.0e38f;
    int bi = 1 << 30;
#pragma unroll 1
    for (int c = 0; c < 8; ++c) {
      const int k = (c << 6) + lane;
      const float* e = emb + (k << 6);
      float acc = 0.f;
#pragma unroll
      for (int j = 0; j < DIM; ++j) acc = fmaf(x[j], e[j], acc);
      const float tt = a2 + b2s[k];  // fl(a2+b2)
      const float u = 2.0f * acc;    // fl(2ab)
      const float d = tt - u;        // fl(t-u)
      if (d < bd || (d == bd && k < bi)) { bd = d; bi = k; }
    }
#pragma unroll
    for (int m = 1; m < 64; m <<= 1) {  // numpy first-min tie rule
      const float od = __shfl_xor(bd, m);
      const int oi = __shfl_xor(bi, m);
      if (od < bd || (od == bd && oi < bi)) { bd = od; bi = oi; }
    }
    if (lane == 0) win[row] = bi;
  }
  __syncthreads();

  {  // fold q into xs in place: batched (8 concurrent emb-row loads/wave)
    const int r0 = wv << 3;
    int wn[8];
#pragma unroll
    for (int r = 0; r < 8; ++r) wn[r] = win[r0 + r];
    float qv[8];
#pragma unroll
    for (int r = 0; r < 8; ++r) qv[r] = emb[(wn[r] << 6) + lane];
#pragma unroll
    for (int r = 0; r < 8; ++r) {
      const float xv = xs[r0 + r][lane];
      xs[r0 + r][lane] = xv + (qv[r] - xv);  // fl(x + fl(q-x))
    }
  }
  __syncthreads();

  {  // store: coalesced, mirror of stage
    const int h = tid & 31, cg = tid >> 5;
    float* obase = out + ((size_t)b << 18) + hw0;
#pragma unroll
    for (int i = 0; i < 8; ++i) {
      const int c = cg + (i << 3);
      obase[((size_t)c << 12) + h] = xs[h][c];
    }
  }
}

// ---- fallback (R3, passed absmax 0.0): used only if ws too small ----
__global__ __launch_bounds__(256, 2) void vq_exact(
    const float* __restrict__ in, const float* __restrict__ emb,
    float* __restrict__ out, int nvec) {
#pragma clang fp contract(off)
  __shared__ float b2s[NEMB];
  for (int r = threadIdx.x; r < NEMB; r += 256) {
    const float* e = emb + r * DIM;
    float rr[8];
#pragma unroll
    for (int j = 0; j < 8; ++j) {
      float acc = e[j] * e[j];
#pragma unroll
      for (int i = 8; i < DIM; i += 8) acc = acc + e[i + j] * e[i + j];
      rr[j] = acc;
    }
    b2s[r] = ((rr[0] + rr[1]) + (rr[2] + rr[3])) + ((rr[4] + rr[5]) + (rr[6] + rr[7]));
  }
  __syncthreads();
  const int vec = blockIdx.x * 256 + threadIdx.x;
  if (vec >= nvec) return;
  const int b = vec >> 12, hw = vec & 4095;
  const float* xp = in + ((size_t)b << 18) + hw;
  float x[DIM];
#pragma unroll
  for (int j = 0; j < DIM; ++j) x[j] = xp[(size_t)j << 12];
  float a2;
  {
    float rr[8];
#pragma unroll
    for (int j = 0; j < 8; ++j) {
      float acc = x[j] * x[j];
#pragma unroll
      for (int i = 8; i < DIM; i += 8) acc = acc + x[i + j] * x[i + j];
      rr[j] = acc;
    }
    a2 = ((rr[0] + rr[1]) + (rr[2] + rr[3])) + ((rr[4] + rr[5]) + (rr[6] + rr[7]));
  }
  float best = 3.0e38f;
  int bi = 0;
  for (int k0 = 0; k0 < NEMB; k0 += 4) {
    const float *e0 = emb + ((k0 + 0) << 6), *e1 = emb + ((k0 + 1) << 6);
    const float *e2 = emb + ((k0 + 2) << 6), *e3 = emb + ((k0 + 3) << 6);
    float c0 = 0.f, c1 = 0.f, c2 = 0.f, c3 = 0.f;
#pragma unroll
    for (int j = 0; j < DIM; ++j) {
      const float xj = x[j];
      c0 = fmaf(xj, e0[j], c0); c1 = fmaf(xj, e1[j], c1);
      c2 = fmaf(xj, e2[j], c2); c3 = fmaf(xj, e3[j], c3);
    }
    float cc[4] = {c0, c1, c2, c3};
#pragma unroll
    for (int q = 0; q < 4; ++q) {
      const float t = a2 + b2s[k0 + q];
      const float u = 2.0f * cc[q];
      const float d = t - u;
      if (d < best) { best = d; bi = k0 + q; }
    }
  }
  const float* ew = emb + (bi << 6);
  float* op = out + ((size_t)b << 18) + hw;
#pragma unroll
  for (int c = 0; c < DIM; ++c) {
    const float xv = x[c];
    op[(size_t)c << 12] = xv + (ew[c] - xv);
  }
}

extern "C" void kernel_launch(void* const* d_in, const int* in_sizes, int n_in,
                              void* d_out, int out_size, void* d_ws, size_t ws_size,
                              hipStream_t stream) {
  const float* in;
  const float* emb;
  int in_elems;
  if (n_in >= 2 && in_sizes[0] == NEMB * DIM && in_sizes[1] != NEMB * DIM) {
    emb = (const float*)d_in[0]; in = (const float*)d_in[1]; in_elems = in_sizes[1];
  } else {
    in = (const float*)d_in[0]; emb = (const float*)d_in[1]; in_elems = in_sizes[0];
  }
  float* out = (float*)d_out;
  const int nvec = in_elems / DIM;
  const size_t swzB = (size_t)NEMB * DIM * 2 * sizeof(u16);  // hi+lo swizzled
  const size_t need = swzB + NEMB * sizeof(float);

  if (ws_size >= need && d_ws != nullptr && (nvec % ROWS) == 0 &&
      (in_elems % (DIM * 4096)) == 0) {
    u16* swz = (u16*)d_ws;
    float* b2 = (float*)((char*)d_ws + swzB);
    vq_prep<<<dim3(NEMB * DIM / 256), dim3(256), 0, stream>>>(emb, swz, b2);
    vq_mfma<<<dim3(nvec / ROWS), dim3(256), 0, stream>>>(in, emb, swz, b2, out);
  } else {
    vq_exact<<<dim3((nvec + 255) / 256), dim3(256), 0, stream>>>(in, emb, out, nvec);
  }
}

// Round 10
// 149.345 us; speedup vs baseline: 1.4421x; 1.0724x over previous
//
#include <hip/hip_runtime.h>

// VectorQuantizer: fp32 buffers. in [32,64,64,64] NCHW, emb [512,64], out
// fp32. Must match numpy fp32 distance argmin bit-for-bit.
// Proven numerics (R11/R12, absmax 0.0, 80.7us best): bf16 hi/lo split
// (exact products), max-domain filter acc' = dot - b2/2 via MFMA acc init,
// index packed in low 9 mantissa bits, med3/max top-3 net, HMARGIN 1.45e-4;
// ambiguous rows -> bit-exact numpy fp32 replica (per-thread top-2 re-rank,
// rare wave-cooperative full rescan).
// R12/R13/R19 3-point pattern: dur tracks codebook-loads-per-row (1x=80.7,
// 2x=96.8/104.4). Kernel is paced by B-fragment load issue/latency, and
// R19's single 6-MFMA chain also exposed MFMA latency.
// R20: 64-row block, 4 waves; each wave = ALL 4 row-tiles x one col-QUARTER
// (128 cols). Same B-loads feed 4 independent MFMA chains: loads/row halve
// vs R12 (block reads codebook exactly once), MFMA latency hidden by 4-way
// ILP. Select VALU count unchanged. Cross-quarter merge = sequential exact
// top-3 inserts (associative pairwise merge). Decision/rescan/fold/store
// identical to proven R12.

#define NEMB 512
#define DIM 64
#define ROWS 64
#define HMARGIN 1.45e-4f  // margin in acc' = -c2/2 (max) domain

typedef unsigned int u32;
typedef unsigned short u16;
typedef __attribute__((ext_vector_type(8))) short bf16x8;
typedef __attribute__((ext_vector_type(4))) float f32x4;

__device__ __forceinline__ u32 f2bfbits(float f) {  // fp32 -> bf16 bits (RNE)
  u32 u = __float_as_uint(f);
  return (u + 0x7FFFu + ((u >> 16) & 1u)) >> 16;
}
__device__ __forceinline__ float bfbits2f(u32 b) {
  return __uint_as_float(b << 16);
}
__device__ __forceinline__ float fmed3(float a, float b, float c) {
  return __builtin_amdgcn_fmed3f(a, b, c);
}

// ---- prep: swizzled hi/lo bf16 codebook + exact numpy-replica b2 ----
// off(g,p,f,r,e) = g*2048 + p*1024 + f*512 + r*32 + e   (u16 units)
//   g=row>>4, r=row&15, p=plane(0 hi,1 lo), f=k>>5, e=k&31.
// 128 blocks x 256 thr (R13-proven parallel form, absmax 0.0); b2 via
// shfl_xor tree == numpy pairwise-8 bit-exactly.
__global__ void vq_prep(const float* __restrict__ emb, u16* __restrict__ swz,
                        float* __restrict__ b2) {
#pragma clang fp contract(off)
  const int gtid = blockIdx.x * 256 + threadIdx.x;  // 0..32767
  {  // swz element task
    const int row = gtid >> 6, k = gtid & 63;
    const float ev = emb[gtid];
    const u32 h = f2bfbits(ev);
    const float res = ev - bfbits2f(h);  // exact (Sterbenz)
    u16* gb = swz + ((row >> 4) << 11) + ((row & 15) << 5);
    const int off2 = ((k >> 5) << 9) + (k & 31);
    gb[off2] = (u16)h;                     // hi plane
    gb[1024 + off2] = (u16)f2bfbits(res);  // lo plane
  }
  if (gtid < NEMB * 8) {  // b2 task: row = gtid>>3, j = gtid&7
    const int row = gtid >> 3, j = gtid & 7;
    const float* e = emb + (row << 6);
    float acc = e[j] * e[j];
#pragma unroll
    for (int i = 8; i < DIM; i += 8) acc = acc + e[i + j] * e[i + j];
    acc = acc + __shfl_xor(acc, 1);  // j=0: rr0+rr1
    acc = acc + __shfl_xor(acc, 2);  // j=0: (rr0+rr1)+(rr2+rr3)
    acc = acc + __shfl_xor(acc, 4);  // j=0: full pairwise-8 combine
    if (j == 0) b2[row] = acc;
  }
}

// ---- main kernel: 64 rows/block, 4 waves.
// wave wv = col-quarter cq (128 cols); each wave computes ALL 4 row-tiles.
__global__ __launch_bounds__(256, 1) void vq_mfma(
    const float* __restrict__ in, const float* __restrict__ emb,
    const u16* __restrict__ swz, const float* __restrict__ b2g,
    float* __restrict__ out) {
#pragma clang fp contract(off)
  __shared__ float xs[ROWS][DIM + 2];
  __shared__ float a2s[ROWS];
  __shared__ float b2s[NEMB];
  __shared__ float wsv1[ROWS][4], wsv2[ROWS][4], wsv3[ROWS][4];
  __shared__ int win[ROWS];
  __shared__ int queue[ROWS];
  __shared__ int qcnt;

  const int tid = threadIdx.x;
  const int blk = blockIdx.x;
  const int b = blk >> 6;
  const int hw0 = (blk & 63) << 6;
  const float* xbase = in + ((size_t)b << 18) + hw0;

  for (int i = tid; i < NEMB; i += 256) b2s[i] = b2g[i];
  if (tid == 0) qcnt = 0;

  {  // stage x tile (64 consecutive floats per wave = coalesced)
    const int h = tid & 63, cg = tid >> 6;
#pragma unroll
    for (int i = 0; i < 16; ++i) {
      const int c = cg + (i << 2);
      xs[h][c] = xbase[((size_t)c << 12) + h];
    }
  }
  __syncthreads();

  if (tid < ROWS) {  // a2 numpy pairwise-8 replica (re-rank input)
    const float* x = xs[tid];
    float rr[8];
#pragma unroll
    for (int j = 0; j < 8; ++j) {
      float acc = x[j] * x[j];
#pragma unroll
      for (int i = 8; i < DIM; i += 8) acc = acc + x[i + j] * x[i + j];
      rr[j] = acc;
    }
    a2s[tid] = ((rr[0] + rr[1]) + (rr[2] + rr[3])) + ((rr[4] + rr[5]) + (rr[6] + rr[7]));
  }

  const int lane = tid & 63;
  const int wv = tid >> 6;
  const int cq = wv;       // col-quarter
  const int rowl = lane & 15;
  const int quad = lane >> 4;

  // A fragments for ALL 4 row-tiles: A[m][k=quad*8+j]
  bf16x8 ah[4][2], al[4][2];
#pragma unroll
  for (int ta = 0; ta < 4; ++ta) {
    const float* xr = xs[(ta << 4) + rowl];
#pragma unroll
    for (int f = 0; f < 2; ++f) {
      const int k0 = (f << 5) + (quad << 3);
      bf16x8 vh, vl;
#pragma unroll
      for (int j = 0; j < 8; ++j) {
        const float xv = xr[k0 + j];
        const u32 h = f2bfbits(xv);
        const float res = xv - bfbits2f(h);  // exact
        vh[j] = (short)h;
        vl[j] = (short)f2bfbits(res);
      }
      ah[ta][f] = vh;
      al[ta][f] = vl;
    }
  }

  // ---- single pass over this quarter's 128 cols: streaming top-3 MAXIMA
  // of acc' = dot - b2/2, index packed in low 9 mantissa bits ----
  float v1[16], v2[16], v3[16];
#pragma unroll
  for (int i = 0; i < 16; ++i) { v1[i] = -3.0e38f; v2[i] = -3.0e38f; v3[i] = -3.0e38f; }

  const u16* cbase = swz + ((size_t)cq << 14);  // 8 col-groups of 2048 u16
  const int off = (rowl << 5) + (quad << 3);

  // 2-deep prefetch: two register sets, manual 2-phase rolled loop
  bf16x8 Ah0 = *(const bf16x8*)(cbase + off);
  bf16x8 Ah1 = *(const bf16x8*)(cbase + 512 + off);
  bf16x8 Al0 = *(const bf16x8*)(cbase + 1024 + off);
  bf16x8 Al1 = *(const bf16x8*)(cbase + 1536 + off);
  bf16x8 Bh0 = *(const bf16x8*)(cbase + 2048 + off);
  bf16x8 Bh1 = *(const bf16x8*)(cbase + 2048 + 512 + off);
  bf16x8 Bl0 = *(const bf16x8*)(cbase + 2048 + 1024 + off);
  bf16x8 Bl1 = *(const bf16x8*)(cbase + 2048 + 1536 + off);

#define VQ_PHASE(TT, PH0, PH1, PL0, PL1)                                      \
  {                                                                           \
    const bf16x8 bh0 = PH0, bh1 = PH1, bl0 = PL0, bl1 = PL1;                  \
    const int tn = (TT) + 2 < 8 ? (TT) + 2 : (TT); /* clamped reload */       \
    const u16* gb = cbase + (tn << 11);                                       \
    PH0 = *(const bf16x8*)(gb + off);                                         \
    PH1 = *(const bf16x8*)(gb + 512 + off);                                   \
    PL0 = *(const bf16x8*)(gb + 1024 + off);                                  \
    PL1 = *(const bf16x8*)(gb + 1536 + off);                                  \
    const int n = (cq << 7) + ((TT) << 4) + rowl;                             \
    const float nb2 = b2s[n] * -0.5f;                                         \
    const u32 nbits = (u32)n;                                                 \
    _Pragma("unroll") for (int ta = 0; ta < 4; ++ta) {                        \
      f32x4 acc = {nb2, nb2, nb2, nb2};                                       \
      acc = __builtin_amdgcn_mfma_f32_16x16x32_bf16(ah[ta][0], bh0, acc, 0, 0, 0); \
      acc = __builtin_amdgcn_mfma_f32_16x16x32_bf16(ah[ta][1], bh1, acc, 0, 0, 0); \
      acc = __builtin_amdgcn_mfma_f32_16x16x32_bf16(ah[ta][0], bl0, acc, 0, 0, 0); \
      acc = __builtin_amdgcn_mfma_f32_16x16x32_bf16(ah[ta][1], bl1, acc, 0, 0, 0); \
      acc = __builtin_amdgcn_mfma_f32_16x16x32_bf16(al[ta][0], bh0, acc, 0, 0, 0); \
      acc = __builtin_amdgcn_mfma_f32_16x16x32_bf16(al[ta][1], bh1, acc, 0, 0, 0); \
      _Pragma("unroll") for (int r = 0; r < 4; ++r) {                         \
        const int i = (ta << 2) + r;                                          \
        const float cp =                                                      \
            __uint_as_float((__float_as_uint(acc[r]) & 0xFFFFFE00u) | nbits); \
        v3[i] = fmed3(v2[i], cp, v3[i]);                                      \
        v2[i] = fmed3(v1[i], cp, v2[i]);                                      \
        v1[i] = fmaxf(v1[i], cp);                                             \
      }                                                                       \
    }                                                                         \
  }

#pragma unroll 1
  for (int t = 0; t < 8; t += 2) {
    VQ_PHASE(t, Ah0, Ah1, Al0, Al1);
    VQ_PHASE(t + 1, Bh0, Bh1, Bl0, Bl1);
  }
#undef VQ_PHASE

  // butterfly top-3 merge across the 16 column lanes (max domain); packed
  // values carry their indices, so the merge is pure med3/max
#pragma unroll
  for (int m = 1; m < 16; m <<= 1) {
#pragma unroll
    for (int i = 0; i < 16; ++i) {
      const float o1 = __shfl_xor(v1[i], m);
      const float o2 = __shfl_xor(v2[i], m);
      const float o3 = __shfl_xor(v3[i], m);
      v3[i] = fmed3(v2[i], o1, v3[i]);
      v2[i] = fmed3(v1[i], o1, v2[i]);
      v1[i] = fmaxf(v1[i], o1);
      v3[i] = fmed3(v2[i], o2, v3[i]);
      v2[i] = fmed3(v1[i], o2, v2[i]);
      v3[i] = fmaxf(v3[i], o3);
    }
  }
  if (rowl == 0) {  // publish per col-quarter slot
#pragma unroll
    for (int ta = 0; ta < 4; ++ta)
#pragma unroll
      for (int r = 0; r < 4; ++r) {
        const int row = (ta << 4) + (quad << 2) + r;
        const int i = (ta << 2) + r;
        wsv1[row][cq] = v1[i]; wsv2[row][cq] = v2[i]; wsv3[row][cq] = v3[i];
      }
  }
  __syncthreads();

  // ---- cross-quarter merge + decision (max domain) ----
  if (tid < ROWS) {
    float m1 = wsv1[tid][0], m2v = wsv2[tid][0], m3 = wsv3[tid][0];
#pragma unroll
    for (int q = 1; q < 4; ++q) {  // sequential exact top-3 pairwise merges
      const float u1 = wsv1[tid][q], u2 = wsv2[tid][q], u3 = wsv3[tid][q];
      m3 = fmed3(m2v, u1, m3);
      m2v = fmed3(m1, u1, m2v);
      m1 = fmaxf(m1, u1);
      m3 = fmed3(m2v, u2, m3);
      m2v = fmed3(m1, u2, m2v);
      m3 = fmaxf(m3, u3);
    }
    const int j1 = (int)(__float_as_uint(m1) & 0x1FFu);
    const int j2 = (int)(__float_as_uint(m2v) & 0x1FFu);

    if (m2v < m1 - HMARGIN) {
      win[tid] = j1;  // unambiguous
    } else if (m3 < m1 - HMARGIN) {
      // true argmin in {j1,j2}: exact numpy fp32 re-rank, first-min tie rule
      const float a2 = a2s[tid];
      const float* x = xs[tid];
      const float* e1p = emb + (j1 << 6);
      const float* e2p = emb + (j2 << 6);
      float acc1 = 0.f, acc2 = 0.f;
#pragma unroll
      for (int j = 0; j < DIM; ++j) {
        acc1 = fmaf(x[j], e1p[j], acc1);
        acc2 = fmaf(x[j], e2p[j], acc2);
      }
      const float t1 = a2 + b2s[j1];
      const float t2 = a2 + b2s[j2];
      const float d1 = t1 - 2.0f * acc1;
      const float d2 = t2 - 2.0f * acc2;
      win[tid] = (d2 < d1 || (d2 == d1 && j2 < j1)) ? j2 : j1;
    } else {  // >=3 within margin: full exact rescan (rare)
      const int p = atomicAdd(&qcnt, 1);
      queue[p] = tid;
    }
  }
  __syncthreads();

  // ---- rare fallback: wave-cooperative bit-exact numpy fp32 rescan ----
  const int nq = qcnt;
  for (int qi = wv; qi < nq; qi += 4) {
    const int row = queue[qi];
    const float a2 = a2s[row];
    const float* x = xs[row];  // broadcast LDS reads
    float bd = 3.0e38f;
    int bi = 1 << 30;
#pragma unroll 1
    for (int c = 0; c < 8; ++c) {
      const int k = (c << 6) + lane;
      const float* e = emb + (k << 6);
      float acc = 0.f;
#pragma unroll
      for (int j = 0; j < DIM; ++j) acc = fmaf(x[j], e[j], acc);
      const float tt = a2 + b2s[k];  // fl(a2+b2)
      const float u = 2.0f * acc;    // fl(2ab)
      const float d = tt - u;        // fl(t-u)
      if (d < bd || (d == bd && k < bi)) { bd = d; bi = k; }
    }
#pragma unroll
    for (int m = 1; m < 64; m <<= 1) {  // numpy first-min tie rule
      const float od = __shfl_xor(bd, m);
      const int oi = __shfl_xor(bi, m);
      if (od < bd || (od == bd && oi < bi)) { bd = od; bi = oi; }
    }
    if (lane == 0) win[row] = bi;
  }
  __syncthreads();

  {  // fold q into xs in place: batched (16 concurrent emb-row loads)
    const int r0 = wv << 4;
    int wn[16];
#pragma unroll
    for (int r = 0; r < 16; ++r) wn[r] = win[r0 + r];
    float qv[16];
#pragma unroll
    for (int r = 0; r < 16; ++r) qv[r] = emb[(wn[r] << 6) + lane];
#pragma unroll
    for (int r = 0; r < 16; ++r) {
      const float xv = xs[r0 + r][lane];
      xs[r0 + r][lane] = xv + (qv[r] - xv);  // fl(x + fl(q-x))
    }
  }
  __syncthreads();

  {  // store: coalesced (lane = h)
    const int h = tid & 63, cg = tid >> 6;
    float* obase = out + ((size_t)b << 18) + hw0;
#pragma unroll
    for (int i = 0; i < 16; ++i) {
      const int c = cg + (i << 2);
      obase[((size_t)c << 12) + h] = xs[h][c];
    }
  }
}

// ---- fallback (R3, passed absmax 0.0): used only if ws too small ----
__global__ __launch_bounds__(256, 2) void vq_exact(
    const float* __restrict__ in, const float* __restrict__ emb,
    float* __restrict__ out, int nvec) {
#pragma clang fp contract(off)
  __shared__ float b2s[NEMB];
  for (int r = threadIdx.x; r < NEMB; r += 256) {
    const float* e = emb + r * DIM;
    float rr[8];
#pragma unroll
    for (int j = 0; j < 8; ++j) {
      float acc = e[j] * e[j];
#pragma unroll
      for (int i = 8; i < DIM; i += 8) acc = acc + e[i + j] * e[i + j];
      rr[j] = acc;
    }
    b2s[r] = ((rr[0] + rr[1]) + (rr[2] + rr[3])) + ((rr[4] + rr[5]) + (rr[6] + rr[7]));
  }
  __syncthreads();
  const int vec = blockIdx.x * 256 + threadIdx.x;
  if (vec >= nvec) return;
  const int b = vec >> 12, hw = vec & 4095;
  const float* xp = in + ((size_t)b << 18) + hw;
  float x[DIM];
#pragma unroll
  for (int j = 0; j < DIM; ++j) x[j] = xp[(size_t)j << 12];
  float a2;
  {
    float rr[8];
#pragma unroll
    for (int j = 0; j < 8; ++j) {
      float acc = x[j] * x[j];
#pragma unroll
      for (int i = 8; i < DIM; i += 8) acc = acc + x[i + j] * x[i + j];
      rr[j] = acc;
    }
    a2 = ((rr[0] + rr[1]) + (rr[2] + rr[3])) + ((rr[4] + rr[5]) + (rr[6] + rr[7]));
  }
  float best = 3.0e38f;
  int bi = 0;
  for (int k0 = 0; k0 < NEMB; k0 += 4) {
    const float *e0 = emb + ((k0 + 0) << 6), *e1 = emb + ((k0 + 1) << 6);
    const float *e2 = emb + ((k0 + 2) << 6), *e3 = emb + ((k0 + 3) << 6);
    float c0 = 0.f, c1 = 0.f, c2 = 0.f, c3 = 0.f;
#pragma unroll
    for (int j = 0; j < DIM; ++j) {
      const float xj = x[j];
      c0 = fmaf(xj, e0[j], c0); c1 = fmaf(xj, e1[j], c1);
      c2 = fmaf(xj, e2[j], c2); c3 = fmaf(xj, e3[j], c3);
    }
    float cc[4] = {c0, c1, c2, c3};
#pragma unroll
    for (int q = 0; q < 4; ++q) {
      const float t = a2 + b2s[k0 + q];
      const float u = 2.0f * cc[q];
      const float d = t - u;
      if (d < best) { best = d; bi = k0 + q; }
    }
  }
  const float* ew = emb + (bi << 6);
  float* op = out + ((size_t)b << 18) + hw;
#pragma unroll
  for (int c = 0; c < DIM; ++c) {
    const float xv = x[c];
    op[(size_t)c << 12] = xv + (ew[c] - xv);
  }
}

extern "C" void kernel_launch(void* const* d_in, const int* in_sizes, int n_in,
                              void* d_out, int out_size, void* d_ws, size_t ws_size,
                              hipStream_t stream) {
  const float* in;
  const float* emb;
  int in_elems;
  if (n_in >= 2 && in_sizes[0] == NEMB * DIM && in_sizes[1] != NEMB * DIM) {
    emb = (const float*)d_in[0]; in = (const float*)d_in[1]; in_elems = in_sizes[1];
  } else {
    in = (const float*)d_in[0]; emb = (const float*)d_in[1]; in_elems = in_sizes[0];
  }
  float* out = (float*)d_out;
  const int nvec = in_elems / DIM;
  const size_t swzB = (size_t)NEMB * DIM * 2 * sizeof(u16);  // hi+lo swizzled
  const size_t need = swzB + NEMB * sizeof(float);

  if (ws_size >= need && d_ws != nullptr && (nvec % ROWS) == 0 &&
      (in_elems % (DIM * 4096)) == 0) {
    u16* swz = (u16*)d_ws;
    float* b2 = (float*)((char*)d_ws + swzB);
    vq_prep<<<dim3(NEMB * DIM / 256), dim3(256), 0, stream>>>(emb, swz, b2);
    vq_mfma<<<dim3(nvec / ROWS), dim3(256), 0, stream>>>(in, emb, swz, b2, out);
  } else {
    vq_exact<<<dim3((nvec + 255) / 256), dim3(256), 0, stream>>>(in, emb, out, nvec);
  }
}